// Round 11
// baseline (117.766 us; speedup 1.0000x reference)
//
#include <hip/hip_runtime.h>

// x: [B=16, T=16384, C=64] fp32. bp_sos/lp_sos: [2,6] fp32 rows (b0,b1,b2,a0,a1,a2; a0==1).
#define B_LEN 16
#define T_LEN 16384
#define C_LEN 64
#define CHUNK 128   // warm amp 1.5x
#define WARM  64    // zero-state warmup; transient ~0.83^64 ~ 7e-6 (empirically safe: absmax 0.0156)

// R16 = R15 with the ring deepened 4x16 -> 6x16 (prefetch distance 64 -> 96
// samples). Unified finding R6..R15: the lever is PREFETCH DISTANCE IN SAMPLES
// (effective load latency ~2600cy ~ 62 samples of issue time; R15's 64 barely
// covers it; R10's dwordx4 failed by quartering distance-per-VGPR). R15 profile
// shows VGPR = 88 = ring64 + y16 + state8 EXACTLY (coef/addr all in SGPRs), so
// 6x16 predicts 120 <= 128 cap at launch_bounds(256,2): no spill, distance
// ~3400cy with slack. Schedule divides cleanly: 12 phases (4 warm + 8 emit),
// groups cycle G0..G5 twice, reloads in phases 0..5 consumed 5 phases later.
// Phase order (compute -> loads -> stores, R9), nt stores, CHUNK=128, 512
// blocks, 8 waves/CU all unchanged from R15 (best, 111.9us).
// Arithmetic order and load/store sets identical -> absmax stays 0.015625.
__global__ __launch_bounds__(256, 2) void iir_pipe_kernel(
    const float* __restrict__ x,
    const float* __restrict__ bp,
    const float* __restrict__ lp,
    float* __restrict__ out)
{
    const int c     = threadIdx.x & 63;        // channel within batch
    const int bsub  = threadIdx.x >> 6;        // 0..3
    const int b     = blockIdx.y * 4 + bsub;   // batch 0..15
    const int chunk = blockIdx.x;              // 0..T/CHUNK-1

    // Uniform coefficients -> scalar (SGPR) loads. a's negated so updates are pure FMA.
    const float b10 = bp[0], b11 = bp[1], b12 = bp[2],  a11 = -bp[4],  a12 = -bp[5];
    const float b20 = bp[6], b21 = bp[7], b22 = bp[8],  a21 = -bp[10], a22 = -bp[11];
    const float b30 = lp[0], b31 = lp[1], b32 = lp[2],  a31 = -lp[4],  a32 = -lp[5];
    const float b40 = lp[6], b41 = lp[7], b42 = lp[8],  a41 = -lp[10], a42 = -lp[11];

    const int t_out0 = chunk * CHUNK;
    const int warm   = (t_out0 < WARM) ? t_out0 : WARM;  // 0 (chunk 0) or 64, block-uniform
    const int t0     = t_out0 - warm;

    // DF2T state: 2 per section
    float s11 = 0.f, s12 = 0.f;
    float s21 = 0.f, s22 = 0.f;
    float s31 = 0.f, s32 = 0.f;
    float s41 = 0.f, s42 = 0.f;

    const float* __restrict__ lq = x   + ((size_t)b * T_LEN + t0)     * C_LEN + c;
    float*       __restrict__ po = out + ((size_t)b * T_LEN + t_out0) * C_LEN + c;

    auto step = [&](float xn) -> float {
        // section 1 (bandpass)
        float y1 = fmaf(b10, xn, s11);
        s11 = fmaf(b11, xn, fmaf(a11, y1, s12));
        s12 = fmaf(b12, xn, a12 * y1);
        // section 2 (bandpass)
        float y2 = fmaf(b20, y1, s21);
        s21 = fmaf(b21, y1, fmaf(a21, y2, s22));
        s22 = fmaf(b22, y1, a22 * y2);
        // squaring nonlinearity
        float v = y2 * y2;
        // section 3 (lowpass)
        float y3 = fmaf(b30, v, s31);
        s31 = fmaf(b31, v, fmaf(a31, y3, s32));
        s32 = fmaf(b32, v, a32 * y3);
        // section 4 (lowpass)
        float y4 = fmaf(b40, y3, s41);
        s41 = fmaf(b41, y3, fmaf(a41, y4, s42));
        s42 = fmaf(b42, y3, a42 * y4);
        return y4;
    };

    // 6x16 register pipeline (96-sample distance). All indices static after unroll.
    float P0[16], P1[16], P2[16], P3[16], P4[16], P5[16];

    auto load16 = [&](float* d) {
#pragma unroll
        for (int j = 0; j < 16; ++j) d[j] = lq[j * C_LEN]; // dword + imm offsets (<=3840)
        lq += 16 * C_LEN;
    };
    auto fence = [&]() { __builtin_amdgcn_sched_barrier(0); };

    auto warm16_reload = [&](float* d) {       // {consume 16 (discard), reload 16}
#pragma unroll
        for (int j = 0; j < 16; ++j) step(d[j]);
        load16(d);
        fence();
    };
    // Emit phase: compute -> prefetch loads -> stores (stores LAST in vmcnt FIFO, R9).
    auto emit16_reload = [&](float* d) {
        float y[16];
#pragma unroll
        for (int j = 0; j < 16; ++j) y[j] = step(d[j]);
        load16(d);         // overwrites d; per-reg anti-dep lets load j trail step j
        fence();           // stores must not be scheduled above the loads
#pragma unroll
        for (int j = 0; j < 16; ++j)
            __builtin_nontemporal_store(y[j], po + j * C_LEN);
        po += 16 * C_LEN;
        fence();
    };
    auto emit16_final = [&](const float* d) {
        float y[16];
#pragma unroll
        for (int j = 0; j < 16; ++j) y[j] = step(d[j]);
#pragma unroll
        for (int j = 0; j < 16; ++j)
            __builtin_nontemporal_store(y[j], po + j * C_LEN);
        po += 16 * C_LEN;
        fence();
    };

    // Prologue: 96 samples in flight (HW throttles issue past 63 outstanding --
    // harmless backpressure at start only).
    load16(P0); load16(P1); load16(P2); load16(P3); load16(P4); load16(P5);
    fence();

    if (warm) {
        // Path A (warm=64): samples t0..t0+192.
        // ph0-3: warm-consume G0..G3 [0,64), reload -> [96,160)
        warm16_reload(P0);
        warm16_reload(P1);
        warm16_reload(P2);
        warm16_reload(P3);
        // ph4-5: emit G4,G5 -> out[0,32), reload -> [160,192) (last load ends
        // exactly at t_out0 + 128 <= T: no OOB)
        emit16_reload(P4);
        emit16_reload(P5);
        // ph6-11: emit G0..G5 -> out[32,128), no reloads.
        emit16_final(P0);
        emit16_final(P1);
        emit16_final(P2);
        emit16_final(P3);
        emit16_final(P4);
        emit16_final(P5);
    } else {
        // Path B (chunk 0, warm=0): samples 0..128.
        // ph0-1: emit G0,G1 -> out[0,32), reload -> [96,128) (ends at 128: no OOB)
        emit16_reload(P0);
        emit16_reload(P1);
        // ph2-7: emit G2..G5,G0,G1 -> out[32,128), no reloads.
        emit16_final(P2);
        emit16_final(P3);
        emit16_final(P4);
        emit16_final(P5);
        emit16_final(P0);
        emit16_final(P1);
    }
}

extern "C" void kernel_launch(void* const* d_in, const int* in_sizes, int n_in,
                              void* d_out, int out_size, void* d_ws, size_t ws_size,
                              hipStream_t stream) {
    const float* x  = (const float*)d_in[0];
    const float* bp = (const float*)d_in[1];
    const float* lp = (const float*)d_in[2];
    float* out      = (float*)d_out;

    dim3 grid(T_LEN / CHUNK, B_LEN / 4);   // 128 x 4 = 512 blocks -> 2 blocks/CU, 8 waves/CU
    dim3 block(256);                        // 4 waves: 4 batches x 64 channels
    iir_pipe_kernel<<<grid, block, 0, stream>>>(x, bp, lp, out);
}